// Round 3
// baseline (471.535 us; speedup 1.0000x reference)
//
#include <hip/hip_runtime.h>
#include <math.h>

// Problem constants (from reference): B=128, T=200, V=10, F=256.
constexpr int NV  = 10;
constexpr int NF  = 256;
constexpr int NC  = NV * NV;   // 100 cells per graph
constexpr int GPB = 4;         // graphs per block = 1 per wave (wave64)
constexpr int PF  = GPB * NV * NF / 4 / 256;  // float4 prefetch regs per thread = 10

// One wave per (b,t) graph; all graph math wave-synchronous. The block's
// end_output slab (40 KB) is prefetched into registers BEFORE the math so the
// HBM stream overlaps the VALU/LDS phases. FW keeps each cell's dist in a
// register, write-through mirrored to LDS for cross-lane row/col-k reads
// (in-place safe: row-k/col-k cells never relax at step k since dist >= 0).
__global__ __launch_bounds__(256) void graph_emb_fused(
    const float* __restrict__ end_output,  // (BT, V, F)
    const float* __restrict__ S,           // (BT, V, V)
    const float* __restrict__ mul,         // (V, V)
    const float* __restrict__ bias,        // (V, V)
    const float* __restrict__ means,       // (1, V)
    const float* __restrict__ stds,        // (1, V)
    const float* __restrict__ emb_in,      // (F, F) rows 0..9 used
    const float* __restrict__ emb_out,     // (F, F)
    const float* __restrict__ emb3,        // (V, V)
    const float* __restrict__ emb4,        // (V, V)
    float* __restrict__ out_main,          // (BT, V, F)
    float* __restrict__ out_atten,         // (BT, V, V)
    int BT)
{
    __shared__ __attribute__((aligned(16))) float s_embsum[NV * NF];
    __shared__ float s_mul[NC], s_bias[NC], s_emb3[NC], s_emb4[NC];
    __shared__ float s_means[NV], s_stds[NV];
    __shared__ float s_dist[GPB][NC];
    __shared__ int   s_si[GPB][NC];
    __shared__ int   s_ei[GPB][NC];
    __shared__ int   s_Di[GPB][NV];

    const int tid  = threadIdx.x;
    const int wave = tid >> 6;
    const int lane = tid & 63;
    const int gbase = blockIdx.x * GPB;
    const int g     = gbase + wave;

    // ---- Prefetch: issue the block's entire end_output slab first ----
    const size_t slab = (size_t)gbase * (NV * NF);
    const float4* end4 = reinterpret_cast<const float4*>(end_output + slab);
    float4*       out4 = reinterpret_cast<float4*>(out_main + slab);
    const bool full = (gbase + GPB <= BT);
    float4 pf[PF];
    if (full) {
        #pragma unroll
        for (int k = 0; k < PF; ++k)
            pf[k] = end4[tid + k * 256];
    }

    // ---- Block-wide table staging (barrier 1 of 2) ----
    for (int idx = tid; idx < NV * NF; idx += 256)
        s_embsum[idx] = emb_in[idx] + emb_out[idx];
    if (tid < NC) {
        s_mul[tid]  = mul[tid];
        s_bias[tid] = bias[tid];
        s_emb3[tid] = emb3[tid];
        s_emb4[tid] = emb4[tid];
    }
    if (tid >= 128 && tid < 128 + NV) {
        s_means[tid - 128] = means[tid - 128];
        s_stds[tid - 128]  = stds[tid - 128];
    }
    __syncthreads();

    // ---- Per-wave graph math (no barriers inside) ----
    if (g < BT) {
        const int g0 = g * NC;
        const int c0 = lane;          // cells 0..63
        const int c1 = 64 + lane;     // cells 64..99 (lane < 36)
        const bool has1 = (lane < 36);
        const int i0 = c0 / NV, j0 = c0 % NV;
        const int i1 = c1 / NV, j1 = c1 % NV;

        // Symmetrize into register + LDS mirror
        float d0 = fminf(S[g0 + c0], S[g0 + j0 * NV + i0]);
        float d1 = 0.f;
        s_dist[wave][c0] = d0;
        if (has1) {
            d1 = fminf(S[g0 + c1], S[g0 + j1 * NV + i1]);
            s_dist[wave][c1] = d1;
        }

        // GaussianLayer edge features -> registers
        const float A = sqrtf(2.0f * 3.14159f);
        float ef0 = 0.f, ef1 = 0.f, sp0 = 0.f, sp1 = 0.f;
        {
            float acc = 0.f;
            #pragma unroll
            for (int j = 0; j < NV; ++j)
                acc += s_dist[wave][i0 * NV + j] * s_mul[j * NV + j0];
            float x = acc + s_bias[c0];
            float z = (x - s_means[j0]) / s_stds[j0];
            float tmp = expf(-0.5f * z * z) / (A * s_stds[j0]);
            float sg = 1.0f / (1.0f + expf(-tmp));
            ef0 = tanhf(sg);
        }
        if (has1) {
            float acc = 0.f;
            #pragma unroll
            for (int j = 0; j < NV; ++j)
                acc += s_dist[wave][i1 * NV + j] * s_mul[j * NV + j1];
            float x = acc + s_bias[c1];
            float z = (x - s_means[j1]) / s_stds[j1];
            float tmp = expf(-0.5f * z * z) / (A * s_stds[j1]);
            float sg = 1.0f / (1.0f + expf(-tmp));
            ef1 = tanhf(sg);
        }

        // Degree buckets (lanes 0..9) from pre-FW dist (== sym)
        if (lane < NV) {
            float d = 0.f;
            #pragma unroll
            for (int i = 0; i < NV; ++i) d += s_dist[wave][i * NV + lane];
            int di = (int)d;   // d in [0,10): trunc == astype(int32)
            s_Di[wave][lane] = min(max(di, 0), NV - 1);
        }

        // Floyd-Warshall: dist in register, write-through to LDS on change
        #pragma unroll
        for (int k = 0; k < NV; ++k) {
            float t0 = s_dist[wave][i0 * NV + k] + s_dist[wave][k * NV + j0];
            if (t0 < d0) { d0 = t0; sp0 += ef0; s_dist[wave][c0] = d0; }
            if (has1) {
                float t1 = s_dist[wave][i1 * NV + k] + s_dist[wave][k * NV + j1];
                if (t1 < d1) { d1 = t1; sp1 += ef1; s_dist[wave][c1] = d1; }
            }
        }

        // Integer buckets
        s_si[wave][c0] = min(max((int)d0, 0), NV - 1);
        s_ei[wave][c0] = min(max((int)sp0, 0), NV - 1);
        if (has1) {
            s_si[wave][c1] = min(max((int)d1, 0), NV - 1);
            s_ei[wave][c1] = min(max((int)sp1, 0), NV - 1);
        }

        // atten_bias = sum_j emb3[Si[i,j]] + emb4[Ei[i,j]]
        {
            float acc3 = 0.f, acc4 = 0.f;
            #pragma unroll
            for (int j = 0; j < NV; ++j) {
                acc3 += s_emb3[s_si[wave][i0 * NV + j] * NV + j0];
                acc4 += s_emb4[s_ei[wave][i0 * NV + j] * NV + j0];
            }
            out_atten[g0 + c0] = acc4 + acc3;
        }
        if (has1) {
            float acc3 = 0.f, acc4 = 0.f;
            #pragma unroll
            for (int j = 0; j < NV; ++j) {
                acc3 += s_emb3[s_si[wave][i1 * NV + j] * NV + j1];
                acc4 += s_emb4[s_ei[wave][i1 * NV + j] * NV + j1];
            }
            out_atten[g0 + c1] = acc4 + acc3;
        }
    }

    // ---- Publish s_Di across waves (barrier 2 of 2), combine + store ----
    __syncthreads();

    const float4* es4 = reinterpret_cast<const float4*>(s_embsum);
    if (full) {
        #pragma unroll
        for (int k = 0; k < PF; ++k) {
            int u   = tid + k * 256;
            int gg  = u / 640;                  // graph within block
            int rem = u - gg * 640;
            int row = rem >> 6;                 // V row
            int f4  = rem & 63;
            float4 e = pf[k];
            float4 s = es4[s_Di[gg][row] * (NF / 4) + f4];
            e.x += s.x; e.y += s.y; e.z += s.z; e.w += s.w;
            out4[u] = e;
        }
    } else {
        const int ng = BT - gbase;              // partial tail block
        const int items = ng * (NV * NF / 4);
        for (int u = tid; u < items; u += 256) {
            int gg  = u / 640;
            int rem = u - gg * 640;
            int row = rem >> 6;
            int f4  = rem & 63;
            float4 e = end4[u];
            float4 s = es4[s_Di[gg][row] * (NF / 4) + f4];
            e.x += s.x; e.y += s.y; e.z += s.z; e.w += s.w;
            out4[u] = e;
        }
    }
}

extern "C" void kernel_launch(void* const* d_in, const int* in_sizes, int n_in,
                              void* d_out, int out_size, void* d_ws, size_t ws_size,
                              hipStream_t stream) {
    const float* end_output = (const float*)d_in[0];
    const float* S          = (const float*)d_in[1];
    const float* mul        = (const float*)d_in[2];
    const float* bias       = (const float*)d_in[3];
    const float* means      = (const float*)d_in[4];
    const float* stds       = (const float*)d_in[5];
    const float* emb_in     = (const float*)d_in[6];
    const float* emb_out    = (const float*)d_in[7];
    const float* emb3       = (const float*)d_in[8];
    const float* emb4       = (const float*)d_in[9];

    float* out_main  = (float*)d_out;
    float* out_atten = out_main + (size_t)in_sizes[0];

    const int BT = in_sizes[1] / (NV * NV);         // 25,600
    const int nblocks = (BT + GPB - 1) / GPB;       // 6,400

    graph_emb_fused<<<nblocks, 256, 0, stream>>>(
        end_output, S, mul, bias, means, stds,
        emb_in, emb_out, emb3, emb4, out_main, out_atten, BT);
}